// Round 8
// baseline (303.741 us; speedup 1.0000x reference)
//
#include <hip/hip_runtime.h>
#include <math.h>
#include <stdint.h>

#define B_ 64
#define J_ 512
#define D_ 1024

typedef __attribute__((ext_vector_type(8))) short short8;
typedef __attribute__((ext_vector_type(4))) float f32x4;

#define GLOBAL_AS __attribute__((address_space(1)))
#define LDS_AS    __attribute__((address_space(3)))

__device__ __forceinline__ void async16(const void* g, void* l) {
    __builtin_amdgcn_global_load_lds((const GLOBAL_AS uint32_t*)g,
                                     (LDS_AS uint32_t*)l, 16, 0, 0);
}

// tanh(x) = 1 - 2/(1+e^{2x}); saturates correctly for |x| large.
__device__ __forceinline__ float fast_tanh(float x) {
    return 1.0f - 2.0f / (1.0f + __expf(2.0f * x));
}

// fp32 -> bf16 round-to-nearest-even
__device__ __forceinline__ unsigned short f2bf(float f) {
    uint32_t u = __builtin_bit_cast(uint32_t, f);
    u += 0x7fffu + ((u >> 16) & 1u);
    return (unsigned short)(u >> 16);
}

// 8 f32 -> short8 bf16 via HW packed convert (RNE), 4 instructions.
__device__ __forceinline__ short8 cvt8(const f32x4 lo, const f32x4 hi) {
    uint32_t w0, w1, w2, w3;
    asm("v_cvt_pk_bf16_f32 %0, %1, %2" : "=v"(w0) : "v"(lo[0]), "v"(lo[1]));
    asm("v_cvt_pk_bf16_f32 %0, %1, %2" : "=v"(w1) : "v"(lo[2]), "v"(lo[3]));
    asm("v_cvt_pk_bf16_f32 %0, %1, %2" : "=v"(w2) : "v"(hi[0]), "v"(hi[1]));
    asm("v_cvt_pk_bf16_f32 %0, %1, %2" : "=v"(w3) : "v"(hi[2]), "v"(hi[3]));
    union { uint32_t u[4]; short8 s; } cv;
    cv.u[0] = w0; cv.u[1] = w1; cv.u[2] = w2; cv.u[3] = w3;
    return cv.s;
}

// ---------------------------------------------------------------------------
// prep: W1[k][n] fp32 -> W1t[n][k] bf16, fused with zeroing of pooled accum.
// ---------------------------------------------------------------------------
__global__ __launch_bounds__(256) void prep_kernel(const float* __restrict__ W1,
                                                   unsigned short* __restrict__ W1t,
                                                   float* __restrict__ pooled) {
    __shared__ float t[32][33];
    const int b   = blockIdx.x;
    const int tid = threadIdx.x;
    if (b < 256) pooled[b * 256 + tid] = 0.f;   // 64*1024 floats total
    const int bx = b & 31, by = b >> 5;
    const int tx = tid & 31, ty = tid >> 5;
    const int n = bx * 32 + tx;
    for (int i = ty; i < 32; i += 8)
        t[i][tx] = W1[(size_t)(by * 32 + i) * D_ + n];
    __syncthreads();
    const int k = by * 32 + tx;
    for (int i = ty; i < 32; i += 8)
        W1t[(size_t)(bx * 32 + i) * D_ + k] = f2bf(t[tx][i]);
}

// ---------------------------------------------------------------------------
// gemm+score kernel — round-6 sync structure (2 __syncthreads per k-step,
// single-buffered LDS, global_load_lds staging), geometry 64(M) x 512(N)
// per n0-step (2 sweeps), BK=64, 8 waves 1x8 over N, wave-tile 64x64.
// ONE change vs round 6: A is staged from f32 x directly into LDS via
// global_load_lds (16 KB f32 tile, pre-swizzled global source, zero
// register traffic, zero global writes) and converted f32->bf16 at
// fragment-read time with v_cvt_pk_bf16_f32. No cast kernel, no Xb.
// ---------------------------------------------------------------------------
__global__ __launch_bounds__(512, 4) void gemm_score_kernel(
    const float* __restrict__ x, const unsigned short* __restrict__ W1t,
    const float* __restrict__ b1, const float* __restrict__ W2,
    const float* __restrict__ b2, const float* __restrict__ mask,
    float* __restrict__ val_ws, float* __restrict__ pooled)
{
    __shared__ __align__(16) float          ldsAf[64 * 64];    // 16 KB [m][k] f32 swz
    __shared__ __align__(16) unsigned short ldsB[512 * 64];    // 64 KB [n][k] bf16 swz

    const int tid  = threadIdx.x;
    const int wave = tid >> 6;        // 0..7 (N-dim)
    const int l    = tid & 63;
    const int l15  = l & 15;
    const int kgrp = l >> 4;
    const int l7   = l & 7;
    const int r0   = blockIdx.x * 64; // 64 rows per block, within one batch
    const int bb   = r0 >> 9;

    // --- A staging (f32): 2 chunks of 16B (4 floats) per thread.
    //     Physical linear chunk q -> row = q>>4, pchunk = q&15; the global
    //     source is pre-swizzled (lchunk = pchunk ^ (row&15)) so the linear
    //     HW write lands the swizzled layout (m173 pattern).
    const int q0r = tid >> 4,          q0c = tid & 15;
    const int q1r = (tid + 512) >> 4,  q1c = tid & 15;   // q1 = tid+512
    const float* gA0 = x + (size_t)(r0 + q0r) * D_ + ((q0c ^ (q0r & 15)) << 2);
    const float* gA1 = x + (size_t)(r0 + q1r) * D_ + ((q1c ^ (q1r & 15)) << 2);
    float* lA0 = ldsAf + (wave << 8);          // +lane*16B by HW
    float* lA1 = lA0 + 2048;                   // second 8 KB half

    // --- B staging: 8 chunks/thread; rows brow + t*64 (+ n0*512) ---
    const int brow = tid >> 3;
    const int bch  = ((tid & 7) ^ (brow & 7)) << 3;
    const unsigned short* gB0 = W1t + (size_t)brow * D_ + bch;
    unsigned short* lB0 = ldsB + (wave << 9);

    // --- fragment LDS offsets, swizzle-consistent ---
    // A (f32 elems): frag(mi,ks) row = mi*16+l15, chunk c0 = ks*8+kgrp*2;
    //   physical = c0 ^ l15; second b128 of the frag at offset ^4 (elems).
    int afo[4][2];
    #pragma unroll
    for (int mi = 0; mi < 4; ++mi)
        #pragma unroll
        for (int ks = 0; ks < 2; ++ks)
            afo[mi][ks] = (mi * 16 + l15) * 64 + (((ks * 8 + kgrp * 2) ^ l15) << 2);
    // B (bf16 elems): as round 6.
    int bbase[2];
    #pragma unroll
    for (int ks = 0; ks < 2; ++ks)
        bbase[ks] = (wave * 64 + l15) * 64 + (((ks * 4 + kgrp) ^ l7) << 3);

    float pv[4][4];
    #pragma unroll
    for (int mi = 0; mi < 4; ++mi)
        #pragma unroll
        for (int r = 0; r < 4; ++r) pv[mi][r] = 0.f;

    for (int n0 = 0; n0 < 2; ++n0) {
        f32x4 acc[4][4];
        #pragma unroll
        for (int mi = 0; mi < 4; ++mi)
            #pragma unroll
            for (int ni = 0; ni < 4; ++ni)
                acc[mi][ni] = (f32x4){0.f, 0.f, 0.f, 0.f};

        const size_t bofs = (size_t)n0 * 512 * D_;
        for (int k0 = 0; k0 < D_; k0 += 64) {
            async16(gA0 + k0, lA0);
            async16(gA1 + k0, lA1);
            #pragma unroll
            for (int t = 0; t < 8; ++t)
                async16(gB0 + bofs + (size_t)t * 64 * D_ + k0, lB0 + t * 4096);
            __syncthreads();
            #pragma unroll
            for (int ks = 0; ks < 2; ++ks) {
                short8 a[4];
                #pragma unroll
                for (int mi = 0; mi < 4; ++mi) {
                    const f32x4 lo = *reinterpret_cast<const f32x4*>(ldsAf + afo[mi][ks]);
                    const f32x4 hi = *reinterpret_cast<const f32x4*>(ldsAf + (afo[mi][ks] ^ 4));
                    a[mi] = cvt8(lo, hi);
                }
                #pragma unroll
                for (int ni = 0; ni < 4; ++ni) {
                    const short8 bv = *reinterpret_cast<const short8*>(
                        ldsB + bbase[ks] + ni * 1024);
                    acc[0][ni] = __builtin_amdgcn_mfma_f32_16x16x32_bf16(a[0], bv, acc[0][ni], 0, 0, 0);
                    acc[1][ni] = __builtin_amdgcn_mfma_f32_16x16x32_bf16(a[1], bv, acc[1][ni], 0, 0, 0);
                    acc[2][ni] = __builtin_amdgcn_mfma_f32_16x16x32_bf16(a[2], bv, acc[2][ni], 0, 0, 0);
                    acc[3][ni] = __builtin_amdgcn_mfma_f32_16x16x32_bf16(a[3], bv, acc[3][ni], 0, 0, 0);
                }
            }
            __syncthreads();
        }

        // fold this 512-col n-tile of h into pv (h never materialized)
        #pragma unroll
        for (int ni = 0; ni < 4; ++ni) {
            const int col = n0 * 512 + wave * 64 + ni * 16 + l15;
            const float b1v = b1[col];
            const float w2v = W2[col];
            #pragma unroll
            for (int mi = 0; mi < 4; ++mi)
                #pragma unroll
                for (int r = 0; r < 4; ++r) {
                    const float h = fast_tanh(acc[mi][ni][r] + b1v);
                    pv[mi][r] = fmaf(h, w2v, pv[mi][r]);
                }
        }
    }

    // --- epilogue (scratch aliased onto ldsB; all MFMA reads are behind the
    //     final __syncthreads of the k-loop) ---
    float* pv_part = reinterpret_cast<float*>(ldsB);   // [8][64]
    float* vrow    = pv_part + 512;                    // [64]

    // reduce pv over the 16 col-lanes (C/D: row = kgrp*4+r, col = l15)
    #pragma unroll
    for (int mi = 0; mi < 4; ++mi)
        #pragma unroll
        for (int r = 0; r < 4; ++r) {
            float s = pv[mi][r];
            s += __shfl_xor(s, 1);
            s += __shfl_xor(s, 2);
            s += __shfl_xor(s, 4);
            s += __shfl_xor(s, 8);
            if (l15 == 0) pv_part[wave * 64 + mi * 16 + kgrp * 4 + r] = s;
        }
    __syncthreads();
    if (tid < 64) {
        float s = b2[0];
        #pragma unroll
        for (int w = 0; w < 8; ++w) s += pv_part[w * 64 + tid];
        const float sg = 1.0f / (1.0f + __expf(-s));
        const float v = sg * mask[r0 + tid];
        val_ws[r0 + tid] = v;
        vrow[tid] = v;
    }
    __syncthreads();

    // unnormalized pooled: pooled[bb][k] += sum_rows x[r][k]*val[r]
    // (x f32, L3-hot — the gemm just streamed it)
    const int kc = tid << 1;
    float a0 = 0.f, a1 = 0.f;
    for (int row = 0; row < 64; ++row) {
        const float v = vrow[row];
        const float2 xv = *reinterpret_cast<const float2*>(
            x + (size_t)(r0 + row) * D_ + kc);
        a0 = fmaf(xv.x, v, a0);
        a1 = fmaf(xv.y, v, a1);
    }
    atomicAdd(&pooled[bb * D_ + kc], a0);
    atomicAdd(&pooled[bb * D_ + kc + 1], a1);
}

// ---------------------------------------------------------------------------
// Fallback fp32 path (used only if ws too small)
// ---------------------------------------------------------------------------
#define MT 64
#define KT 32
#define PAD 68

__global__ __launch_bounds__(256) void score_kernel_fp32(
    const float* __restrict__ x, const float* __restrict__ mask,
    const float* __restrict__ W1, const float* __restrict__ b1,
    const float* __restrict__ W2, const float* __restrict__ b2,
    float* __restrict__ val_ws, float* __restrict__ pooled)
{
    __shared__ float As[KT][PAD];
    __shared__ float Bs[KT][PAD];
    __shared__ float red[MT][17];
    __shared__ float vrow[MT];

    const int tid = threadIdx.x;
    const int tx = tid & 15;
    const int ty = tid >> 4;
    const int r0 = blockIdx.x * MT;
    const int b  = r0 >> 9;

    float pv[4] = {0.f, 0.f, 0.f, 0.f};

    for (int n0 = 0; n0 < D_; n0 += 64) {
        float acc[4][4];
        #pragma unroll
        for (int i = 0; i < 4; ++i)
            #pragma unroll
            for (int j = 0; j < 4; ++j) acc[i][j] = 0.f;

        for (int k0 = 0; k0 < D_; k0 += KT) {
            #pragma unroll
            for (int ll = 0; ll < 2; ++ll) {
                const int f   = tid + ll * 256;
                const int row = f >> 3;
                const int k4  = (f & 7) << 2;
                const float4 xv = *reinterpret_cast<const float4*>(
                    &x[(size_t)(r0 + row) * D_ + k0 + k4]);
                As[k4 + 0][row] = xv.x;
                As[k4 + 1][row] = xv.y;
                As[k4 + 2][row] = xv.z;
                As[k4 + 3][row] = xv.w;
            }
            #pragma unroll
            for (int ll = 0; ll < 2; ++ll) {
                const int f  = tid + ll * 256;
                const int k  = f >> 4;
                const int n4 = (f & 15) << 2;
                const float4 wv = *reinterpret_cast<const float4*>(
                    &W1[(size_t)(k0 + k) * D_ + n0 + n4]);
                *reinterpret_cast<float4*>(&Bs[k][n4]) = wv;
            }
            __syncthreads();
            #pragma unroll
            for (int kk = 0; kk < KT; ++kk) {
                const float4 a4 = *reinterpret_cast<const float4*>(&As[kk][ty << 2]);
                const float4 b4 = *reinterpret_cast<const float4*>(&Bs[kk][tx << 2]);
                const float av[4] = {a4.x, a4.y, a4.z, a4.w};
                const float bv[4] = {b4.x, b4.y, b4.z, b4.w};
                #pragma unroll
                for (int i = 0; i < 4; ++i)
                    #pragma unroll
                    for (int j = 0; j < 4; ++j)
                        acc[i][j] = fmaf(av[i], bv[j], acc[i][j]);
            }
            __syncthreads();
        }
        #pragma unroll
        for (int j = 0; j < 4; ++j) {
            const int col = n0 + (tx << 2) + j;
            const float b1v = b1[col];
            const float w2v = W2[col];
            #pragma unroll
            for (int i = 0; i < 4; ++i) {
                const float h = fast_tanh(acc[i][j] + b1v);
                pv[i] = fmaf(h, w2v, pv[i]);
            }
        }
    }

    #pragma unroll
    for (int i = 0; i < 4; ++i) red[(ty << 2) + i][tx] = pv[i];
    __syncthreads();

    if (tid < MT) {
        float s = 0.f;
        #pragma unroll
        for (int t = 0; t < 16; ++t) s += red[tid][t];
        const float z  = s + b2[0];
        const float sg = 1.0f / (1.0f + __expf(-z));
        const float v  = sg * mask[r0 + tid];
        val_ws[r0 + tid] = v;
        vrow[tid] = v;
    }
    __syncthreads();

    const int k = tid << 2;
    float a0 = 0.f, a1 = 0.f, a2 = 0.f, a3 = 0.f;
    for (int row = 0; row < MT; ++row) {
        const float v = vrow[row];
        const float4 xv = *reinterpret_cast<const float4*>(
            &x[(size_t)(r0 + row) * D_ + k]);
        a0 = fmaf(xv.x, v, a0);
        a1 = fmaf(xv.y, v, a1);
        a2 = fmaf(xv.z, v, a2);
        a3 = fmaf(xv.w, v, a3);
    }
    float* pb = &pooled[b * D_ + k];
    atomicAdd(pb + 0, a0);
    atomicAdd(pb + 1, a1);
    atomicAdd(pb + 2, a2);
    atomicAdd(pb + 3, a3);
}

__global__ __launch_bounds__(256) void finalize_kernel(
    const float* __restrict__ val_ws, const float* __restrict__ pooled,
    const float* __restrict__ W3, const float* __restrict__ b3,
    float* __restrict__ out)
{
    __shared__ float sred[256];
    const int b = blockIdx.x;
    const int tid = threadIdx.x;

    const float v0 = val_ws[b * J_ + tid];
    const float v1 = val_ws[b * J_ + 256 + tid];
    sred[tid] = v0 + v1;
    __syncthreads();
    for (int s = 128; s > 0; s >>= 1) {
        if (tid < s) sred[tid] += sred[tid + s];
        __syncthreads();
    }
    const float inv = 1.0f / sred[0];

    out[192 + b * J_ + tid]       = v0 * inv;
    out[192 + b * J_ + 256 + tid] = v1 * inv;

    const int k = tid << 2;
    float acc3[3] = {0.f, 0.f, 0.f};
    #pragma unroll
    for (int c = 0; c < 4; ++c) {
        const float p = pooled[b * D_ + k + c] * inv;
        acc3[0] = fmaf(p, W3[(k + c) * 3 + 0], acc3[0]);
        acc3[1] = fmaf(p, W3[(k + c) * 3 + 1], acc3[1]);
        acc3[2] = fmaf(p, W3[(k + c) * 3 + 2], acc3[2]);
    }
    for (int o = 0; o < 3; ++o) {
        __syncthreads();
        sred[tid] = acc3[o];
        __syncthreads();
        for (int s = 128; s > 0; s >>= 1) {
            if (tid < s) sred[tid] += sred[tid + s];
            __syncthreads();
        }
        if (tid == 0) out[b * 3 + o] = sred[0] + b3[o];
    }
}

extern "C" void kernel_launch(void* const* d_in, const int* in_sizes, int n_in,
                              void* d_out, int out_size, void* d_ws, size_t ws_size,
                              hipStream_t stream) {
    const float* x    = (const float*)d_in[0];
    const float* mask = (const float*)d_in[1];
    const float* W1   = (const float*)d_in[2];
    const float* b1   = (const float*)d_in[3];
    const float* W2   = (const float*)d_in[4];
    const float* b2   = (const float*)d_in[5];
    const float* W3   = (const float*)d_in[6];
    const float* b3   = (const float*)d_in[7];
    float* out = (float*)d_out;

    const size_t W1T_BYTES  = (size_t)D_ * D_ * 2;        //  2,097,152
    const size_t VAL_BYTES  = (size_t)B_ * J_ * 4;        //    131,072
    const size_t POOL_BYTES = (size_t)B_ * D_ * 4;        //    262,144
    const size_t NEED = W1T_BYTES + VAL_BYTES + POOL_BYTES;

    if (ws_size >= NEED) {
        unsigned short* W1t = (unsigned short*)d_ws;
        float* val_ws = (float*)((char*)d_ws + W1T_BYTES);
        float* pooled = (float*)((char*)d_ws + W1T_BYTES + VAL_BYTES);

        prep_kernel<<<1024, 256, 0, stream>>>(W1, W1t, pooled);
        gemm_score_kernel<<<512, 512, 0, stream>>>(x, W1t, b1, W2, b2, mask,
                                                   val_ws, pooled);
        finalize_kernel<<<B_, 256, 0, stream>>>(val_ws, pooled, W3, b3, out);
    } else {
        float* val_ws = (float*)d_ws;
        float* pooled = val_ws + B_ * J_;
        hipMemsetAsync(pooled, 0, POOL_BYTES, stream);
        score_kernel_fp32<<<(B_ * J_) / MT, 256, 0, stream>>>(
            x, mask, W1, b1, W2, b2, val_ws, pooled);
        finalize_kernel<<<B_, 256, 0, stream>>>(val_ws, pooled, W3, b3, out);
    }
}